// Round 6
// baseline (366.447 us; speedup 1.0000x reference)
//
#include <hip/hip_runtime.h>
#include <stdint.h>
#include <math.h>

typedef float fx4 __attribute__((ext_vector_type(4)));
typedef short sx8 __attribute__((ext_vector_type(8)));
typedef __bf16 bfx8 __attribute__((ext_vector_type(8)));
typedef unsigned short ux4 __attribute__((ext_vector_type(4)));

#define NB 4096
#define ND 1024
#define CEPS 1e-6f
#define CTHR 0.5f
#define NT 16            // K-tiles of 64: 1024/64

// ---------- helpers ----------

__device__ __forceinline__ unsigned short f2bf(float f) {
  uint32_t u = __builtin_bit_cast(uint32_t, f);
  u = u + 0x7FFFu + ((u >> 16) & 1u);   // RNE
  return (unsigned short)(u >> 16);
}

__device__ __forceinline__ void gload16(const void* g, void* l) {
  __builtin_amdgcn_global_load_lds(
      (const __attribute__((address_space(1))) uint32_t*)(uintptr_t)g,
      (__attribute__((address_space(3))) uint32_t*)(uint32_t)(uintptr_t)l,
      16, 0, 0);
}

__device__ __forceinline__ bfx8 ldfrag(const void* p) {
  sx8 r = *(const sx8*)p;
  return __builtin_bit_cast(bfx8, r);
}

#define MFMA(A, B, C) __builtin_amdgcn_mfma_f32_16x16x32_bf16((A), (B), (C), 0, 0, 0)

// ---------- kernel 1: f32 -> bf16 convert + row norms (f32) ----------

__global__ __launch_bounds__(256) void cmc_convert(
    const float* __restrict__ in, unsigned short* __restrict__ xb,
    float* __restrict__ lnorm) {
  const int row = blockIdx.x;           // 0 .. 3*4096-1
  const int tid = threadIdx.x;
  const fx4 v = *(const fx4*)(in + (size_t)row * ND + tid * 4);
  ux4 o;
  o[0] = f2bf(v[0]); o[1] = f2bf(v[1]); o[2] = f2bf(v[2]); o[3] = f2bf(v[3]);
  *(ux4*)(xb + (size_t)row * ND + tid * 4) = o;
  float ss = v[0]*v[0] + v[1]*v[1] + v[2]*v[2] + v[3]*v[3];
  #pragma unroll
  for (int d = 1; d < 64; d <<= 1) ss += __shfl_xor(ss, d);
  __shared__ float sred[4];
  if ((tid & 63) == 0) sred[tid >> 6] = ss;
  __syncthreads();
  if (tid == 0) lnorm[row] = sqrtf(sred[0] + sred[1] + sred[2] + sred[3]);
}

// ---------- 256x256 gram, BK=64, 4 WAVES (128x128 per wave), dbuf ----------
// LDS per buffer (2 x 64 KiB): A [256 rows][64 bf16 =128 B] @+0, B @+32768.
// XOR swizzle: byte (row, c) stored at row*128 + (c ^ ((row&7)<<4)).
// global_load_lds dest is linear; the SOURCE col is pre-swizzled (rule 21).
// Design point: frag-read traffic = waves*(m+n) = 4*16 = 64 KB per K-32
// (vs 96 KB for the 8-wave 2x4 grid) -> LDS pipe ~balanced with MFMA pipe.

__device__ __forceinline__ void stage_tile(char* dst, int t,
    const unsigned short* gA, const unsigned short* gB) {
  const int k0 = t * 64;
  #pragma unroll
  for (int s = 0; s < 8; ++s) {
    gload16(gA + (size_t)s * 32 * ND + k0, dst + s * 4096);
    gload16(gB + (size_t)s * 32 * ND + k0, dst + 32768 + s * 4096);
  }
}

template<bool LAST>
__device__ __forceinline__ void ktile(
    char* smem, int t,
    const unsigned short* gA, const unsigned short* gB,
    const char* bA, const char* bB, int cA0, int cA1, int cB0, int cB1,
    fx4 (&acc)[8][8]) {
  const char* bufA = bA + (t & 1) * 65536;
  const char* bufB = bB + (t & 1) * 65536;

  // gate: this tile's 16 gloads landed (counted; 16 = next tile's in flight)
  if (LAST) asm volatile("s_waitcnt vmcnt(0)" ::: "memory");
  else      asm volatile("s_waitcnt vmcnt(16)" ::: "memory");
  __builtin_amdgcn_sched_barrier(0);
  __builtin_amdgcn_s_barrier();
  __builtin_amdgcn_sched_barrier(0);

  #pragma unroll
  for (int kh = 0; kh < 2; ++kh) {
    const int ca = kh ? cA1 : cA0;
    const int cb = kh ? cB1 : cB0;
    bfx8 bfr[8];
    #pragma unroll
    for (int n = 0; n < 8; ++n) bfr[n] = ldfrag(bufB + n * 2048 + cb);
    #pragma unroll
    for (int m = 0; m < 8; ++m) {
      const bfx8 am = ldfrag(bufA + m * 2048 + ca);
      #pragma unroll
      for (int n = 0; n < 8; ++n) acc[m][n] = MFMA(am, bfr[n], acc[m][n]);
    }
  }

  // all my LDS reads done, then block-wide: buf[t&1] free for restaging
  asm volatile("s_waitcnt lgkmcnt(0)" ::: "memory");
  __builtin_amdgcn_sched_barrier(0);
  __builtin_amdgcn_s_barrier();
  __builtin_amdgcn_sched_barrier(0);
  if (t + 2 < NT) stage_tile((char*)(smem + (t & 1) * 65536), t + 2, gA, gB);
}

__device__ __forceinline__ void gram256(
    const unsigned short* __restrict__ Xi, const unsigned short* __restrict__ Xj,
    int rb, int cb, char* smem, int tid, fx4 (&acc)[8][8]) {
  const int l = tid & 63, w = tid >> 6;
  const int wr = w >> 1, wc = w & 1;     // wave grid 2 x 2
  // staging: thread covers dest bytes [pass*4096 + tid*16); row = pass*32 + (tid>>3)
  const int srow = tid >> 3;             // row within 32-row pass stripe
  const int scol = ((tid & 7) * 16) ^ ((srow & 7) << 4);   // pre-swizzled src bytes
  const unsigned short* gA = Xi + (size_t)(rb + srow) * ND + (scol >> 1);
  const unsigned short* gB = Xj + (size_t)(cb + srow) * ND + (scol >> 1);
  char* dst0 = smem + tid * 16;

  // frag read addressing: row = base + (l&15); swizzle term = (l&7)<<4
  const int swz = (l & 7) << 4;
  const int c0 = (l >> 4) * 16;
  const char* bA = smem + (wr * 128 + (l & 15)) * 128;
  const char* bB = smem + 32768 + (wc * 128 + (l & 15)) * 128;
  const int cA0 = c0 ^ swz, cA1 = (64 + c0) ^ swz;

  #pragma unroll
  for (int m = 0; m < 8; ++m)
    #pragma unroll
    for (int n = 0; n < 8; ++n) acc[m][n] = fx4{0.f, 0.f, 0.f, 0.f};

  stage_tile(dst0, 0, gA, gB);           // 16 gloads
  stage_tile(dst0 + 65536, 1, gA, gB);   // 16 gloads -> 32 outstanding

  #pragma unroll 1
  for (int t = 0; t < NT - 1; ++t)
    ktile<false>(dst0, t, gA, gB, bA, bB, cA0, cA1, cA0, cA1, acc);
  ktile<true>(dst0, NT - 1, gA, gB, bA, bB, cA0, cA1, cA0, cA1, acc);
}

// ---------- kernel 2: per-modal self-gram -> bitmask (upper-tri + transpose) ----------

__global__ __launch_bounds__(256, 1) void cmc_selfmask(
    const unsigned short* __restrict__ xb, const float* __restrict__ lnorm,
    uint32_t* __restrict__ maskw) {
  __shared__ __align__(16) char smem[131072];
  const int md = blockIdx.z;
  const int bx = blockIdx.x, by = blockIdx.y;
  if (by > bx) return;                   // symmetric: upper triangle only
  const int rb = by * 256, cb = bx * 256;
  const int tid = threadIdx.x;
  const int l = tid & 63, w = tid >> 6;
  const int wr = w >> 1, wc = w & 1;
  const int g = l >> 4;

  const unsigned short* X = xb + (size_t)md * NB * ND;
  fx4 acc[8][8];
  gram256(X, X, rb, cb, smem, tid, acc);

  // threshold -> 256x256 bit tile in LDS (smem free after gram's last barrier)
  uint32_t* tile = (uint32_t*)smem;      // [256][8] words = 8 KiB
  float* Lr = (float*)(smem + 8192);
  float* Lc = (float*)(smem + 9216);
  if (tid < 256) {
    Lr[tid] = lnorm[md * NB + rb + tid];
    Lc[tid] = lnorm[md * NB + cb + tid];
  }
  __syncthreads();

  #pragma unroll
  for (int m = 0; m < 8; ++m)
    #pragma unroll
    for (int r4 = 0; r4 < 4; ++r4) {
      const int rl = wr * 128 + m * 16 + g * 4 + r4;
      uint64_t bb[8];
      #pragma unroll
      for (int n = 0; n < 8; ++n) {
        const int cl = wc * 128 + n * 16 + (l & 15);
        const float cv = acc[m][n][r4] / fmaxf(Lr[rl] * Lc[cl], CEPS);
        bb[n] = __ballot(cv <= CTHR);
      }
      if ((l & 15) == 0) {
        #pragma unroll
        for (int q = 0; q < 4; ++q) {
          const uint32_t wv = (uint32_t)((bb[2*q] >> (16 * g)) & 0xFFFF) |
                              ((uint32_t)((bb[2*q+1] >> (16 * g)) & 0xFFFF) << 16);
          tile[rl * 8 + wc * 4 + q] = wv;
        }
      }
    }
  __syncthreads();

  // direct region: rows [rb,+256) x words [cb/32,+8) — exclusively owned
  for (int t = tid; t < 2048; t += 256) {
    const int row = t >> 3, wd = t & 7;
    maskw[((size_t)md * NB + rb + row) * 128 + (cb >> 5) + wd] = tile[t];
  }
  // transposed region: rows [cb,+256) x words [rb/32,+8)
  if (by != bx) {
    for (int t = tid; t < 2048; t += 256) {
      const int crow = t & 255;
      const int wp = t >> 8;
      uint32_t wv = 0;
      #pragma unroll
      for (int r = 0; r < 32; ++r) {
        const uint32_t bit = (tile[(wp * 32 + r) * 8 + (crow >> 5)] >> (crow & 31)) & 1u;
        wv |= bit << r;
      }
      maskw[((size_t)md * NB + cb + crow) * 128 + (rb >> 5) + wp] = wv;
    }
  }
}

// ---------- kernel 3: per-pair cross gram + masked exp row-partials ----------

__global__ __launch_bounds__(256, 1) void cmc_pair(
    const unsigned short* __restrict__ xb, const float* __restrict__ lnorm,
    const uint32_t* __restrict__ maskw,
    float* __restrict__ sumexp, float* __restrict__ diagv) {
  __shared__ __align__(16) char smem[131072];
  const int p = blockIdx.z;              // pair: 0->(0,1) 1->(0,2) 2->(1,2)
  const int mi = (p == 2) ? 1 : 0;
  const int mj = (p == 0) ? 1 : 2;
  const int rb = blockIdx.y * 256;
  const int cb = blockIdx.x * 256;
  const int tid = threadIdx.x;
  const int l = tid & 63, w = tid >> 6;
  const int wr = w >> 1, wc = w & 1;
  const int g = l >> 4;

  const unsigned short* Xi = xb + (size_t)mi * NB * ND;
  const unsigned short* Xj = xb + (size_t)mj * NB * ND;

  fx4 acc[8][8];
  gram256(Xi, Xj, rb, cb, smem, tid, acc);

  // stage masks + norms into LDS (smem free after gram)
  uint32_t* Mt = (uint32_t*)smem;        // Mi [256][8] then Mj [256][8]
  float* Lri = (float*)(smem + 16384);
  float* Lcj = (float*)(smem + 17408);
  for (int t = tid; t < 2048; t += 256) {
    const int row = t >> 3, wd = t & 7;
    Mt[t]        = maskw[((size_t)mi * NB + rb + row) * 128 + (cb >> 5) + wd];
    Mt[2048 + t] = maskw[((size_t)mj * NB + rb + row) * 128 + (cb >> 5) + wd];
  }
  if (tid < 256) {
    Lri[tid] = lnorm[mi * NB + rb + tid];
    Lcj[tid] = lnorm[mj * NB + cb + tid];
  }
  __syncthreads();

  #pragma unroll
  for (int m = 0; m < 8; ++m)
    #pragma unroll
    for (int r4 = 0; r4 < 4; ++r4) {
      const int rl = wr * 128 + m * 16 + g * 4 + r4;
      const int rg = rb + rl;
      const float Lrv = Lri[rl];
      float se = 0.f;
      #pragma unroll
      for (int n = 0; n < 8; ++n) {
        const int cl = wc * 128 + n * 16 + (l & 15);
        const int cg = cb + cl;
        const uint32_t bi = (Mt[rl * 8 + (cl >> 5)] >> (cl & 31)) & 1u;
        const uint32_t bj = (Mt[2048 + rl * 8 + (cl >> 5)] >> (cl & 31)) & 1u;
        const bool msk = bi | bj | (rg == cg);
        const float logit = acc[m][n][r4] / fmaxf(Lrv * Lcj[cl], CEPS) * 10.0f;
        if (rg == cg) diagv[p * NB + rg] = logit;
        if (msk) se += __expf(logit);
      }
      #pragma unroll
      for (int d0 = 1; d0 < 16; d0 <<= 1) se += __shfl_xor(se, d0);
      if ((l & 15) == 0) atomicAdd(&sumexp[p * NB + rg], se);
    }
}

// ---------- kernel 4: per-row mask popcount ----------

__global__ __launch_bounds__(256) void cmc_count(
    const uint32_t* __restrict__ maskw, float* __restrict__ cntrow) {
  const int wid = (blockIdx.x * 256 + threadIdx.x) >> 6;  // one wave per row
  const int l = threadIdx.x & 63;
  const int p = wid >> 12;
  const int r = wid & 4095;
  const int mi = (p == 2) ? 1 : 0;
  const int mj = (p == 0) ? 1 : 2;
  int cnt = 0;
  #pragma unroll
  for (int h = 0; h < 2; ++h) {
    const int wd = h * 64 + l;
    uint32_t v = maskw[((size_t)mi * NB + r) * 128 + wd] |
                 maskw[((size_t)mj * NB + r) * 128 + wd];
    if ((r >> 5) == wd) v |= (1u << (r & 31));   // diagonal always kept
    cnt += __popc(v);
  }
  #pragma unroll
  for (int d = 1; d < 64; d <<= 1) cnt += __shfl_xor(cnt, d);
  if (l == 0) cntrow[p * NB + r] = (float)cnt;
}

// ---------- kernel 5: finalize ----------

__global__ __launch_bounds__(256) void cmc_final(
    const float* __restrict__ sumexp, const float* __restrict__ cntrow,
    const float* __restrict__ diagv, float* __restrict__ out) {
  const int tid = threadIdx.x;
  __shared__ float sred[8];
  float lsum = 0.f;
  for (int p = 0; p < 3; ++p) {
    float t = 0.f, c = 0.f;
    for (int r = tid; r < NB; r += 256) {
      const float cnt = cntrow[p * NB + r];
      if (cnt > 1.0f) {
        t += logf(sumexp[p * NB + r]) - diagv[p * NB + r];
        c += 1.f;
      }
    }
    #pragma unroll
    for (int d = 1; d < 64; d <<= 1) { t += __shfl_xor(t, d); c += __shfl_xor(c, d); }
    if ((tid & 63) == 0) { sred[(tid >> 6) * 2] = t; sred[(tid >> 6) * 2 + 1] = c; }
    __syncthreads();
    if (tid == 0) {
      const float tt = sred[0] + sred[2] + sred[4] + sred[6];
      const float cc = sred[1] + sred[3] + sred[5] + sred[7];
      lsum += (cc > 0.f) ? tt / fmaxf(cc, 1.f) : 0.f;
    }
    __syncthreads();
  }
  if (tid == 0) out[0] = lsum / 3.0f;
}

// ---------- launch ----------

extern "C" void kernel_launch(void* const* d_in, const int* in_sizes, int n_in,
                              void* d_out, int out_size, void* d_ws, size_t ws_size,
                              hipStream_t stream) {
  const float* in = (const float*)d_in[0];
  float* out = (float*)d_out;
  char* ws = (char*)d_ws;

  const size_t XB_BYTES = (size_t)3 * NB * ND * sizeof(unsigned short); // 25,165,824
  unsigned short* xb = (unsigned short*)ws;
  float* lnorm  = (float*)(ws + XB_BYTES);
  float* sumexp = lnorm + 3 * NB;
  float* cntrow = sumexp + 3 * NB;
  float* diagv  = cntrow + 3 * NB;
  uint32_t* maskw = (uint32_t*)(diagv + 3 * NB);   // [3][4096][128] words = 6 MB

  hipMemsetAsync(sumexp, 0, (size_t)3 * NB * sizeof(float), stream);

  cmc_convert<<<3 * NB, 256, 0, stream>>>(in, xb, lnorm);
  cmc_selfmask<<<dim3(NB / 256, NB / 256, 3), 256, 0, stream>>>(xb, lnorm, maskw);
  cmc_pair<<<dim3(NB / 256, NB / 256, 3), 256, 0, stream>>>(xb, lnorm, maskw, sumexp, diagv);
  cmc_count<<<3 * NB / 4, 256, 0, stream>>>(maskw, cntrow);
  cmc_final<<<1, 256, 0, stream>>>(sumexp, cntrow, diagv, out);
}

// Round 7
// 299.934 us; speedup vs baseline: 1.2218x; 1.2218x over previous
//
#include <hip/hip_runtime.h>
#include <stdint.h>
#include <math.h>

typedef float fx4 __attribute__((ext_vector_type(4)));
typedef short sx8 __attribute__((ext_vector_type(8)));
typedef __bf16 bfx8 __attribute__((ext_vector_type(8)));
typedef unsigned short ux4 __attribute__((ext_vector_type(4)));

#define NB 4096
#define ND 1024
#define CEPS 1e-6f
#define CTHR 0.5f
#define NITER 8          // iterations of 2 K-tiles (BK=64): 1024 / 128

// ---------- helpers ----------

__device__ __forceinline__ unsigned short f2bf(float f) {
  uint32_t u = __builtin_bit_cast(uint32_t, f);
  u = u + 0x7FFFu + ((u >> 16) & 1u);   // RNE
  return (unsigned short)(u >> 16);
}

__device__ __forceinline__ void gload16(const void* g, void* l) {
  __builtin_amdgcn_global_load_lds(
      (const __attribute__((address_space(1))) uint32_t*)(uintptr_t)g,
      (__attribute__((address_space(3))) uint32_t*)(uint32_t)(uintptr_t)l,
      16, 0, 0);
}

__device__ __forceinline__ bfx8 ldfrag(const void* p) {
  sx8 r = *(const sx8*)p;
  return __builtin_bit_cast(bfx8, r);
}

#define MFMA(A, B, C) __builtin_amdgcn_mfma_f32_16x16x32_bf16((A), (B), (C), 0, 0, 0)

// ---------- kernel 1: f32 -> bf16 convert + row norms (f32) ----------

__global__ __launch_bounds__(256) void cmc_convert(
    const float* __restrict__ in, unsigned short* __restrict__ xb,
    float* __restrict__ lnorm) {
  const int row = blockIdx.x;           // 0 .. 3*4096-1
  const int tid = threadIdx.x;
  const fx4 v = *(const fx4*)(in + (size_t)row * ND + tid * 4);
  ux4 o;
  o[0] = f2bf(v[0]); o[1] = f2bf(v[1]); o[2] = f2bf(v[2]); o[3] = f2bf(v[3]);
  *(ux4*)(xb + (size_t)row * ND + tid * 4) = o;
  float ss = v[0]*v[0] + v[1]*v[1] + v[2]*v[2] + v[3]*v[3];
  #pragma unroll
  for (int d = 1; d < 64; d <<= 1) ss += __shfl_xor(ss, d);
  __shared__ float sred[4];
  if ((tid & 63) == 0) sred[tid >> 6] = ss;
  __syncthreads();
  if (tid == 0) lnorm[row] = sqrtf(sred[0] + sred[1] + sred[2] + sred[3]);
}

// ---------- 256x256 gram, 8 waves (2Mx4N), 8-phase schedule, BK=64 ----------
//
// LDS = 8 half-slabs of 16 KiB (total 128 KiB):
//   A(d,kh) at (d*2+kh)*16384          d = tile parity, kh = K-half (32 elems)
//   B(d,kh) at 65536 + (d*2+kh)*16384
// Slab layout: [256 rows][32 bf16 = 64 B], byte (r,c) stored at r*64 + (c ^ ((r&3)<<4)).
// Staging (global_load_lds, linear dest): thread tid covers stored bytes
// s*8192 + tid*16; source col pre-swizzled with the same XOR (rule #21).
//
// Iteration i: tiles e=2i (buf0, phases 1-4) and o=2i+1 (buf1, phases 5-8).
// Phase (kh, m-half): reads 4 A-frags (+4 B-frags at the first phase of each kh),
// stages per the rolling schedule, then {gate?}, barrier, 16 MFMA, barrier.
//
// Stage schedule (slab is dead 1+ phase before restage; see per-line proof):
//   P1: A(o,kh1)+B(o,kh1)   [buf1.kh1 dead since prev-iter P8]
//   P3: A(e+2,kh0)          [buf0.A.kh0 read P1,P2 only]
//   P4: B(e+2,kh0)          [buf0.B.kh0 read P1 only]      GATE vmcnt(4)
//   P5: A(e+2,kh1)+B(e+2,kh1) [buf0.kh1 read P3,P4 only]
//   P7: A(o+2,kh0)          [buf1.A.kh0 read P5,P6 only]
//   P8: B(o+2,kh0)          [buf1.B.kh0 read P5 only]      GATE vmcnt(4)
// Ledger: at P4, unproven-newest-4 = {P3,P4}; proves {prevP7,prevP8,P1} = all of o.
//         at P8, unproven-newest-4 = {P7,P8}; proves {P3,P4,P5} = all of e+2.
// Every read of a slab occurs in the 4-phase window after its proving gate.

__device__ __forceinline__ void stageA(char* smem, const unsigned short* sA,
                                       int t, int kh, int tid) {
  char* dst = smem + ((t & 1) * 2 + kh) * 16384 + tid * 16;
  const unsigned short* g = sA + (size_t)t * 64 + kh * 32;
  gload16(g, dst);
  gload16(g + (size_t)128 * ND, dst + 8192);
}
__device__ __forceinline__ void stageB(char* smem, const unsigned short* sB,
                                       int t, int kh, int tid) {
  char* dst = smem + 65536 + ((t & 1) * 2 + kh) * 16384 + tid * 16;
  const unsigned short* g = sB + (size_t)t * 64 + kh * 32;
  gload16(g, dst);
  gload16(g + (size_t)128 * ND, dst + 8192);
}

template<int PH, bool LAST>
__device__ __forceinline__ void phase(char* smem, int T,
    const unsigned short* sA, const unsigned short* sB, int tid,
    const char* rdA, const char* rdB, bfx8 (&bfr)[4], fx4 (&acc)[8][4]) {
  constexpr int d    = (PH <= 4) ? 0 : 1;
  constexpr int kh   = ((PH - 1) >> 1) & 1;
  constexpr int mh   = (PH - 1) & 1;
  constexpr int slab = (d * 2 + kh) * 16384;

  // 1. ds_reads for THIS phase (latency hidden under the barrier wait)
  bfx8 a[4];
  #pragma unroll
  for (int m = 0; m < 4; ++m)
    a[m] = ldfrag(rdA + slab + (mh * 4 + m) * 1024);
  if (mh == 0) {
    #pragma unroll
    for (int n = 0; n < 4; ++n)
      bfr[n] = ldfrag(rdB + slab + n * 1024);
  }
  // 2. stage half-slabs (rolling)
  if (PH == 1)          { stageA(smem, sA, T + 1, 1, tid); stageB(smem, sB, T + 1, 1, tid); }
  if (!LAST) {
    if (PH == 3)          stageA(smem, sA, T + 2, 0, tid);
    if (PH == 4)          stageB(smem, sB, T + 2, 0, tid);
    if (PH == 5)        { stageA(smem, sA, T + 2, 1, tid); stageB(smem, sB, T + 2, 1, tid); }
    if (PH == 7)          stageA(smem, sA, T + 3, 0, tid);
    if (PH == 8)          stageB(smem, sB, T + 3, 0, tid);
  }
  // 3. counted gates (asm "memory" walls also fence read hoisting across gates)
  if (PH == 4) {
    if (LAST) asm volatile("s_waitcnt vmcnt(0)" ::: "memory");
    else      asm volatile("s_waitcnt vmcnt(4)" ::: "memory");
  }
  if (PH == 8 && !LAST) asm volatile("s_waitcnt vmcnt(4)" ::: "memory");
  // 4. barrier (raw: no vmcnt(0)/lgkmcnt(0) drain)
  __builtin_amdgcn_s_barrier();
  // 5. 16 MFMA (compiler inserts fine-grained lgkmcnt for a[]/bfr[] deps)
  __builtin_amdgcn_s_setprio(1);
  #pragma unroll
  for (int m = 0; m < 4; ++m)
    #pragma unroll
    for (int n = 0; n < 4; ++n)
      acc[mh * 4 + m][n] = MFMA(a[m], bfr[n], acc[mh * 4 + m][n]);
  __builtin_amdgcn_s_setprio(0);
  // 6. closing barrier (makes next phase's restage of dead slabs safe)
  __builtin_amdgcn_s_barrier();
}

template<bool LAST>
__device__ __forceinline__ void iter8(char* smem, int T,
    const unsigned short* sA, const unsigned short* sB, int tid,
    const char* rdA, const char* rdB, bfx8 (&bfr)[4], fx4 (&acc)[8][4]) {
  phase<1, LAST>(smem, T, sA, sB, tid, rdA, rdB, bfr, acc);
  phase<2, LAST>(smem, T, sA, sB, tid, rdA, rdB, bfr, acc);
  phase<3, LAST>(smem, T, sA, sB, tid, rdA, rdB, bfr, acc);
  phase<4, LAST>(smem, T, sA, sB, tid, rdA, rdB, bfr, acc);
  phase<5, LAST>(smem, T, sA, sB, tid, rdA, rdB, bfr, acc);
  phase<6, LAST>(smem, T, sA, sB, tid, rdA, rdB, bfr, acc);
  phase<7, LAST>(smem, T, sA, sB, tid, rdA, rdB, bfr, acc);
  phase<8, LAST>(smem, T, sA, sB, tid, rdA, rdB, bfr, acc);
}

__device__ __forceinline__ void gram256(
    const unsigned short* __restrict__ Xi, const unsigned short* __restrict__ Xj,
    int rb, int cb, char* smem, int tid, fx4 (&acc)[8][4]) {
  const int l = tid & 63, w = tid >> 6;
  const int wr = w >> 2, wc = w & 3;     // wave grid 2M x 4N
  // staging source (pre-swizzled): thread row = tid>>2, stored col = (tid&3)*16
  const int srcswz = (((tid & 3) * 16) ^ (((tid >> 2) & 3) << 4)) >> 1; // elems
  const unsigned short* sA = Xi + (size_t)(rb + (tid >> 2)) * ND + srcswz;
  const unsigned short* sB = Xj + (size_t)(cb + (tid >> 2)) * ND + srcswz;
  // frag read bases: row = base + (l&15); stored col = ((l>>4) ^ (l&3)) << 4
  const int sc = (((l >> 4) ^ (l & 3)) << 4);
  const char* rdA = smem + (wr * 128 + (l & 15)) * 64 + sc;
  const char* rdB = smem + 65536 + (wc * 64 + (l & 15)) * 64 + sc;

  #pragma unroll
  for (int m = 0; m < 8; ++m)
    #pragma unroll
    for (int n = 0; n < 4; ++n) acc[m][n] = fx4{0.f, 0.f, 0.f, 0.f};

  // prologue: tile0 (all 4 halves) + tile1 kh0 — matches steady-state P7'/P8'
  stageA(smem, sA, 0, 0, tid); stageB(smem, sB, 0, 0, tid);
  stageA(smem, sA, 0, 1, tid); stageB(smem, sB, 0, 1, tid);
  stageA(smem, sA, 1, 0, tid); stageB(smem, sB, 1, 0, tid);
  asm volatile("s_waitcnt vmcnt(4)" ::: "memory");   // tile0 proven; t1.kh0 in flight
  __builtin_amdgcn_s_barrier();

  bfx8 bfr[4];
  #pragma unroll 1
  for (int i = 0; i < NITER - 1; ++i)
    iter8<false>(smem, 2 * i, sA, sB, tid, rdA, rdB, bfr, acc);
  iter8<true>(smem, 2 * (NITER - 1), sA, sB, tid, rdA, rdB, bfr, acc);
}

// ---------- kernel 2: per-modal self-gram -> bitmask (upper-tri + transpose) ----------

__global__ __launch_bounds__(512, 2) void cmc_selfmask(
    const unsigned short* __restrict__ xb, const float* __restrict__ lnorm,
    uint32_t* __restrict__ maskw) {
  __shared__ __align__(16) char smem[131072];
  const int md = blockIdx.z;
  const int bx = blockIdx.x, by = blockIdx.y;
  if (by > bx) return;                   // symmetric: upper triangle only
  const int rb = by * 256, cb = bx * 256;
  const int tid = threadIdx.x;
  const int l = tid & 63, w = tid >> 6;
  const int wr = w >> 2, wc = w & 3;
  const int g = l >> 4;

  const unsigned short* X = xb + (size_t)md * NB * ND;
  fx4 acc[8][4];
  gram256(X, X, rb, cb, smem, tid, acc);
  __syncthreads();                       // full drain before smem reuse

  uint32_t* tile = (uint32_t*)smem;      // [256][8] words = 8 KiB
  float* Lr = (float*)(smem + 8192);
  float* Lc = (float*)(smem + 9216);
  if (tid < 256) {
    Lr[tid] = lnorm[md * NB + rb + tid];
    Lc[tid] = lnorm[md * NB + cb + tid];
  }
  __syncthreads();

  #pragma unroll
  for (int m = 0; m < 8; ++m)
    #pragma unroll
    for (int r4 = 0; r4 < 4; ++r4) {
      const int rl = wr * 128 + m * 16 + g * 4 + r4;
      uint64_t bb[4];
      #pragma unroll
      for (int n = 0; n < 4; ++n) {
        const int cl = wc * 64 + n * 16 + (l & 15);
        const float cv = acc[m][n][r4] / fmaxf(Lr[rl] * Lc[cl], CEPS);
        bb[n] = __ballot(cv <= CTHR);
      }
      if ((l & 15) == 0) {
        const uint32_t w0 = (uint32_t)((bb[0] >> (16 * g)) & 0xFFFF) |
                            ((uint32_t)((bb[1] >> (16 * g)) & 0xFFFF) << 16);
        const uint32_t w1 = (uint32_t)((bb[2] >> (16 * g)) & 0xFFFF) |
                            ((uint32_t)((bb[3] >> (16 * g)) & 0xFFFF) << 16);
        tile[rl * 8 + wc * 2]     = w0;
        tile[rl * 8 + wc * 2 + 1] = w1;
      }
    }
  __syncthreads();

  for (int t = tid; t < 2048; t += 512) {
    const int row = t >> 3, wd = t & 7;
    maskw[((size_t)md * NB + rb + row) * 128 + (cb >> 5) + wd] = tile[t];
  }
  if (by != bx) {
    for (int t = tid; t < 2048; t += 512) {
      const int crow = t & 255;
      const int wp = t >> 8;
      uint32_t wv = 0;
      #pragma unroll
      for (int r = 0; r < 32; ++r) {
        const uint32_t bit = (tile[(wp * 32 + r) * 8 + (crow >> 5)] >> (crow & 31)) & 1u;
        wv |= bit << r;
      }
      maskw[((size_t)md * NB + cb + crow) * 128 + (rb >> 5) + wp] = wv;
    }
  }
}

// ---------- kernel 3: per-pair cross gram + masked exp row-partials ----------

__global__ __launch_bounds__(512, 2) void cmc_pair(
    const unsigned short* __restrict__ xb, const float* __restrict__ lnorm,
    const uint32_t* __restrict__ maskw,
    float* __restrict__ sumexp, float* __restrict__ diagv) {
  __shared__ __align__(16) char smem[131072];
  const int p = blockIdx.z;              // pair: 0->(0,1) 1->(0,2) 2->(1,2)
  const int mi = (p == 2) ? 1 : 0;
  const int mj = (p == 0) ? 1 : 2;
  const int rb = blockIdx.y * 256;
  const int cb = blockIdx.x * 256;
  const int tid = threadIdx.x;
  const int l = tid & 63, w = tid >> 6;
  const int wr = w >> 2, wc = w & 3;
  const int g = l >> 4;

  const unsigned short* Xi = xb + (size_t)mi * NB * ND;
  const unsigned short* Xj = xb + (size_t)mj * NB * ND;

  fx4 acc[8][4];
  gram256(Xi, Xj, rb, cb, smem, tid, acc);
  __syncthreads();                       // full drain before smem reuse

  uint32_t* Mt = (uint32_t*)smem;        // Mi [256][8] then Mj [256][8]
  float* Lri = (float*)(smem + 16384);
  float* Lcj = (float*)(smem + 17408);
  for (int t = tid; t < 2048; t += 512) {
    const int row = t >> 3, wd = t & 7;
    Mt[t]        = maskw[((size_t)mi * NB + rb + row) * 128 + (cb >> 5) + wd];
    Mt[2048 + t] = maskw[((size_t)mj * NB + rb + row) * 128 + (cb >> 5) + wd];
  }
  if (tid < 256) {
    Lri[tid] = lnorm[mi * NB + rb + tid];
    Lcj[tid] = lnorm[mj * NB + cb + tid];
  }
  __syncthreads();

  #pragma unroll
  for (int m = 0; m < 8; ++m)
    #pragma unroll
    for (int r4 = 0; r4 < 4; ++r4) {
      const int rl = wr * 128 + m * 16 + g * 4 + r4;
      const int rg = rb + rl;
      const float Lrv = Lri[rl];
      float se = 0.f;
      #pragma unroll
      for (int n = 0; n < 4; ++n) {
        const int cl = wc * 64 + n * 16 + (l & 15);
        const int cg = cb + cl;
        const uint32_t bi = (Mt[rl * 8 + (cl >> 5)] >> (cl & 31)) & 1u;
        const uint32_t bj = (Mt[2048 + rl * 8 + (cl >> 5)] >> (cl & 31)) & 1u;
        const bool msk = bi | bj | (rg == cg);
        const float logit = acc[m][n][r4] / fmaxf(Lrv * Lcj[cl], CEPS) * 10.0f;
        if (rg == cg) diagv[p * NB + rg] = logit;
        if (msk) se += __expf(logit);
      }
      #pragma unroll
      for (int d0 = 1; d0 < 16; d0 <<= 1) se += __shfl_xor(se, d0);
      if ((l & 15) == 0) atomicAdd(&sumexp[p * NB + rg], se);
    }
}

// ---------- kernel 4: per-row mask popcount ----------

__global__ __launch_bounds__(256) void cmc_count(
    const uint32_t* __restrict__ maskw, float* __restrict__ cntrow) {
  const int wid = (blockIdx.x * 256 + threadIdx.x) >> 6;  // one wave per row
  const int l = threadIdx.x & 63;
  const int p = wid >> 12;
  const int r = wid & 4095;
  const int mi = (p == 2) ? 1 : 0;
  const int mj = (p == 0) ? 1 : 2;
  int cnt = 0;
  #pragma unroll
  for (int h = 0; h < 2; ++h) {
    const int wd = h * 64 + l;
    uint32_t v = maskw[((size_t)mi * NB + r) * 128 + wd] |
                 maskw[((size_t)mj * NB + r) * 128 + wd];
    if ((r >> 5) == wd) v |= (1u << (r & 31));   // diagonal always kept
    cnt += __popc(v);
  }
  #pragma unroll
  for (int d = 1; d < 64; d <<= 1) cnt += __shfl_xor(cnt, d);
  if (l == 0) cntrow[p * NB + r] = (float)cnt;
}

// ---------- kernel 5: finalize ----------

__global__ __launch_bounds__(256) void cmc_final(
    const float* __restrict__ sumexp, const float* __restrict__ cntrow,
    const float* __restrict__ diagv, float* __restrict__ out) {
  const int tid = threadIdx.x;
  __shared__ float sred[8];
  float lsum = 0.f;
  for (int p = 0; p < 3; ++p) {
    float t = 0.f, c = 0.f;
    for (int r = tid; r < NB; r += 256) {
      const float cnt = cntrow[p * NB + r];
      if (cnt > 1.0f) {
        t += logf(sumexp[p * NB + r]) - diagv[p * NB + r];
        c += 1.f;
      }
    }
    #pragma unroll
    for (int d = 1; d < 64; d <<= 1) { t += __shfl_xor(t, d); c += __shfl_xor(c, d); }
    if ((tid & 63) == 0) { sred[(tid >> 6) * 2] = t; sred[(tid >> 6) * 2 + 1] = c; }
    __syncthreads();
    if (tid == 0) {
      const float tt = sred[0] + sred[2] + sred[4] + sred[6];
      const float cc = sred[1] + sred[3] + sred[5] + sred[7];
      lsum += (cc > 0.f) ? tt / fmaxf(cc, 1.f) : 0.f;
    }
    __syncthreads();
  }
  if (tid == 0) out[0] = lsum / 3.0f;
}

// ---------- launch ----------

extern "C" void kernel_launch(void* const* d_in, const int* in_sizes, int n_in,
                              void* d_out, int out_size, void* d_ws, size_t ws_size,
                              hipStream_t stream) {
  const float* in = (const float*)d_in[0];
  float* out = (float*)d_out;
  char* ws = (char*)d_ws;

  const size_t XB_BYTES = (size_t)3 * NB * ND * sizeof(unsigned short); // 25,165,824
  unsigned short* xb = (unsigned short*)ws;
  float* lnorm  = (float*)(ws + XB_BYTES);
  float* sumexp = lnorm + 3 * NB;
  float* cntrow = sumexp + 3 * NB;
  float* diagv  = cntrow + 3 * NB;
  uint32_t* maskw = (uint32_t*)(diagv + 3 * NB);   // [3][4096][128] words = 6 MB

  hipMemsetAsync(sumexp, 0, (size_t)3 * NB * sizeof(float), stream);

  cmc_convert<<<3 * NB, 256, 0, stream>>>(in, xb, lnorm);
  cmc_selfmask<<<dim3(NB / 256, NB / 256, 3), 512, 0, stream>>>(xb, lnorm, maskw);
  cmc_pair<<<dim3(NB / 256, NB / 256, 3), 512, 0, stream>>>(xb, lnorm, maskw, sumexp, diagv);
  cmc_count<<<3 * NB / 4, 256, 0, stream>>>(maskw, cntrow);
  cmc_final<<<1, 256, 0, stream>>>(sumexp, cntrow, diagv, out);
}

// Round 8
// 241.836 us; speedup vs baseline: 1.5153x; 1.2402x over previous
//
#include <hip/hip_runtime.h>
#include <stdint.h>
#include <math.h>

typedef float fx4 __attribute__((ext_vector_type(4)));
typedef float fx16 __attribute__((ext_vector_type(16)));
typedef int   ix4 __attribute__((ext_vector_type(4)));
typedef int   ix8 __attribute__((ext_vector_type(8)));

#define NB 4096
#define ND 1024
#define CEPS 1e-6f
#define CTHR 0.5f
#define NTT 16           // K-tiles of 64: 1024/64

// ---------- helpers ----------

__device__ __forceinline__ void gload16(const void* g, void* l) {
  __builtin_amdgcn_global_load_lds(
      (const __attribute__((address_space(1))) uint32_t*)(uintptr_t)g,
      (__attribute__((address_space(3))) uint32_t*)(uint32_t)(uintptr_t)l,
      16, 0, 0);
}

__device__ __forceinline__ ix8 ldfrag8(const char* p0, const char* p1) {
  const ix4 lo = *(const ix4*)p0;
  const ix4 hi = *(const ix4*)p1;
  ix8 r;
  r[0] = lo[0]; r[1] = lo[1]; r[2] = lo[2]; r[3] = lo[3];
  r[4] = hi[0]; r[5] = hi[1]; r[6] = hi[2]; r[7] = hi[3];
  return r;
}

// fp8 e4m3 (OCP on gfx950), scales = 127 (x1.0) — validated in R4
#define MFMAS(A, B, C) \
  __builtin_amdgcn_mfma_scale_f32_32x32x64_f8f6f4((A), (B), (C), 0, 0, 0, 127, 0, 127)

// ---------- kernel 1: f32 -> fp8 convert + row norms (f32) ----------

__global__ __launch_bounds__(256) void cmc_convert(
    const float* __restrict__ in, uint8_t* __restrict__ xf8,
    float* __restrict__ lnorm) {
  const int row = blockIdx.x;           // 0 .. 3*4096-1
  const int tid = threadIdx.x;
  const fx4 v = *(const fx4*)(in + (size_t)row * ND + tid * 4);
  int pk = __builtin_amdgcn_cvt_pk_fp8_f32(v[0], v[1], 0, false);
  pk = __builtin_amdgcn_cvt_pk_fp8_f32(v[2], v[3], pk, true);
  ((int*)(xf8 + (size_t)row * ND))[tid] = pk;
  float ss = v[0]*v[0] + v[1]*v[1] + v[2]*v[2] + v[3]*v[3];
  #pragma unroll
  for (int d = 1; d < 64; d <<= 1) ss += __shfl_xor(ss, d);
  __shared__ float sred[4];
  if ((tid & 63) == 0) sred[tid >> 6] = ss;
  __syncthreads();
  if (tid == 0) lnorm[row] = sqrtf(sred[0] + sred[1] + sred[2] + sred[3]);
}

// ---------- 128x128 fp8 gram, BK=64, 4 waves (64x64 each), single-buffer ----------
// LDS 16 KiB: A [128 rows][64 B] @0, B @8192.
// Swizzle: stored_byte(r,c) = r*64 + (c ^ (((r>>1)&3)<<4))  -> even 16B-slot
// spread for the 32-row frag reads (8 lanes per slot-class per b128: free).
// Staging: linear dest (global_load_lds), source col pre-swizzled (rule #21).
// m97-style loop: stage(t); __syncthreads (drain); reads+MFMA; __syncthreads.
// The drain stall is hidden by 3-4 co-resident blocks per CU (the m114/m97
// implicit-overlap mechanism — the round that finally matches the model).

__device__ __forceinline__ void gram128_f8(
    const uint8_t* __restrict__ Xi, const uint8_t* __restrict__ Xj,
    int rb, int cb, char* smem, int tid, fx16 (&acc)[2][2]) {
  const int l = tid & 63, w = tid >> 6;
  const int wr = w >> 1, wc = w & 1;     // wave grid 2 x 2, wave tile 64x64
  // staging: thread covers dest bytes tid*16 of each 4 KiB half-slab
  const int srow = tid >> 2;             // 0..63
  const int scol = (((tid & 3) ^ ((tid >> 3) & 3)) << 4);  // pre-swizzled src col
  const uint8_t* gA0 = Xi + (size_t)(rb + srow) * ND + scol;
  const uint8_t* gA1 = Xi + (size_t)(rb + 64 + srow) * ND + scol;
  const uint8_t* gB0 = Xj + (size_t)(cb + srow) * ND + scol;
  const uint8_t* gB1 = Xj + (size_t)(cb + 64 + srow) * ND + scol;
  char* dA0 = smem + tid * 16;
  char* dA1 = smem + 4096 + tid * 16;
  char* dB0 = smem + 8192 + tid * 16;
  char* dB1 = smem + 12288 + tid * 16;

  // frag reads: A frag m -> rows wr*64 + m*32 + (l&31); k-bytes (l>>5)*32 .. +31
  const int swzl = ((l >> 1) & 3) << 4;                    // ((r>>1)&3)<<4, r = ..+(l&31)
  const int kb = (l >> 5) * 32;
  const int c0 = kb ^ swzl;
  const int c1 = (kb + 16) ^ swzl;
  const char* rdA = smem + (wr * 64 + (l & 31)) * 64;
  const char* rdB = smem + 8192 + (wc * 64 + (l & 31)) * 64;

  #pragma unroll
  for (int m = 0; m < 2; ++m)
    #pragma unroll
    for (int n = 0; n < 2; ++n)
      #pragma unroll
      for (int e = 0; e < 16; ++e) acc[m][n][e] = 0.f;

  #pragma unroll 1
  for (int t = 0; t < NTT; ++t) {
    const int k0 = t * 64;
    gload16(gA0 + k0, dA0);
    gload16(gA1 + k0, dA1);
    gload16(gB0 + k0, dB0);
    gload16(gB1 + k0, dB1);
    __syncthreads();                     // drains vmcnt(0): tile landed
    ix8 A[2], B[2];
    #pragma unroll
    for (int m = 0; m < 2; ++m)
      A[m] = ldfrag8(rdA + m * 2048 + c0, rdA + m * 2048 + c1);
    #pragma unroll
    for (int n = 0; n < 2; ++n)
      B[n] = ldfrag8(rdB + n * 2048 + c0, rdB + n * 2048 + c1);
    #pragma unroll
    for (int m = 0; m < 2; ++m)
      #pragma unroll
      for (int n = 0; n < 2; ++n)
        acc[m][n] = MFMAS(A[m], B[n], acc[m][n]);
    __syncthreads();                     // all reads consumed before restage
  }
}

// ---------- kernel 2: per-modal self-gram -> bitmask (upper-tri + transpose) ----------

__global__ __launch_bounds__(256, 3) void cmc_selfmask(
    const uint8_t* __restrict__ xf8, const float* __restrict__ lnorm,
    uint32_t* __restrict__ maskw) {
  __shared__ __align__(16) char smem[16384];
  const int md = blockIdx.z;
  const int bx = blockIdx.x, by = blockIdx.y;
  if (by > bx) return;                   // symmetric: upper triangle only
  const int rb = by * 128, cb = bx * 128;
  const int tid = threadIdx.x;
  const int l = tid & 63, w = tid >> 6;
  const int wr = w >> 1, wc = w & 1;

  const uint8_t* X = xf8 + (size_t)md * NB * ND;
  fx16 acc[2][2];
  gram128_f8(X, X, rb, cb, smem, tid, acc);

  // threshold -> 128x128 bit tile in LDS (smem free after gram's final sync)
  uint32_t* tile = (uint32_t*)smem;      // [128][4] words = 2 KiB
  float* Lr = (float*)(smem + 2048);
  float* Lc = (float*)(smem + 2560 + 512);
  if (tid < 128) {
    Lr[tid] = lnorm[md * NB + rb + tid];
    Lc[tid] = lnorm[md * NB + cb + tid];
  }
  __syncthreads();

  #pragma unroll
  for (int m = 0; m < 2; ++m)
    #pragma unroll
    for (int r = 0; r < 16; ++r) {
      const int rl0 = wr * 64 + m * 32 + (r & 3) + 8 * (r >> 2);  // + 4*(l>>5)
      const float Lrv = Lr[rl0 + 4 * (l >> 5)];
      #pragma unroll
      for (int n = 0; n < 2; ++n) {
        const int cl = wc * 64 + n * 32 + (l & 31);
        const float cv = acc[m][n][r] / fmaxf(Lrv * Lc[cl], CEPS);
        const uint64_t b = __ballot(cv <= CTHR);
        if (l == 0)  tile[(rl0 + 0) * 4 + wc * 2 + n] = (uint32_t)b;
        if (l == 32) tile[(rl0 + 4) * 4 + wc * 2 + n] = (uint32_t)(b >> 32);
      }
    }
  __syncthreads();

  // direct region: rows [rb,+128) x words [cb/32,+4) — exclusively owned
  for (int t = tid; t < 512; t += 256) {
    const int row = t >> 2, wd = t & 3;
    maskw[((size_t)md * NB + rb + row) * 128 + (cb >> 5) + wd] = tile[t];
  }
  // transposed region: rows [cb,+128) x words [rb/32,+4)
  if (by != bx) {
    for (int t = tid; t < 512; t += 256) {
      const int crow = t & 127;
      const int wp = t >> 7;
      uint32_t wv = 0;
      #pragma unroll
      for (int r = 0; r < 32; ++r) {
        const uint32_t bit = (tile[(wp * 32 + r) * 4 + (crow >> 5)] >> (crow & 31)) & 1u;
        wv |= bit << r;
      }
      maskw[((size_t)md * NB + cb + crow) * 128 + (rb >> 5) + wp] = wv;
    }
  }
}

// ---------- kernel 3: per-pair cross gram + masked exp row-partials ----------

__global__ __launch_bounds__(256, 3) void cmc_pair(
    const uint8_t* __restrict__ xf8, const float* __restrict__ lnorm,
    const uint32_t* __restrict__ maskw,
    float* __restrict__ sumexp, float* __restrict__ diagv) {
  __shared__ __align__(16) char smem[16384];
  const int p = blockIdx.z;              // pair: 0->(0,1) 1->(0,2) 2->(1,2)
  const int mi = (p == 2) ? 1 : 0;
  const int mj = (p == 0) ? 1 : 2;
  const int rb = blockIdx.y * 128;
  const int cb = blockIdx.x * 128;
  const int tid = threadIdx.x;
  const int l = tid & 63, w = tid >> 6;
  const int wr = w >> 1, wc = w & 1;

  const uint8_t* Xi = xf8 + (size_t)mi * NB * ND;
  const uint8_t* Xj = xf8 + (size_t)mj * NB * ND;

  fx16 acc[2][2];
  gram128_f8(Xi, Xj, rb, cb, smem, tid, acc);

  // stage masks + norms into LDS (smem free after gram's final sync)
  uint32_t* Mt = (uint32_t*)smem;        // Mi [128][4] then Mj [128][4]
  float* Lri = (float*)(smem + 4096);
  float* Lcj = (float*)(smem + 4608 + 512);
  for (int t = tid; t < 512; t += 256) {
    const int row = t >> 2, wd = t & 3;
    Mt[t]       = maskw[((size_t)mi * NB + rb + row) * 128 + (cb >> 5) + wd];
    Mt[512 + t] = maskw[((size_t)mj * NB + rb + row) * 128 + (cb >> 5) + wd];
  }
  if (tid < 128) {
    Lri[tid] = lnorm[mi * NB + rb + tid];
    Lcj[tid] = lnorm[mj * NB + cb + tid];
  }
  __syncthreads();

  #pragma unroll
  for (int m = 0; m < 2; ++m)
    #pragma unroll
    for (int r = 0; r < 16; ++r) {
      const int rl = wr * 64 + m * 32 + (r & 3) + 8 * (r >> 2) + 4 * (l >> 5);
      const int rg = rb + rl;
      const float Lrv = Lri[rl];
      float se = 0.f;
      #pragma unroll
      for (int n = 0; n < 2; ++n) {
        const int cl = wc * 64 + n * 32 + (l & 31);
        const int cg = cb + cl;
        const uint32_t bi = (Mt[rl * 4 + (cl >> 5)] >> (cl & 31)) & 1u;
        const uint32_t bj = (Mt[512 + rl * 4 + (cl >> 5)] >> (cl & 31)) & 1u;
        const bool msk = bi | bj | (rg == cg);
        const float logit = acc[m][n][r] / fmaxf(Lrv * Lcj[cl], CEPS) * 10.0f;
        if (rg == cg) diagv[p * NB + rg] = logit;
        if (msk) se += __expf(logit);
      }
      #pragma unroll
      for (int d = 1; d < 32; d <<= 1) se += __shfl_xor(se, d);
      if ((l & 31) == 0) atomicAdd(&sumexp[p * NB + rg], se);
    }
}

// ---------- kernel 4: per-row mask popcount ----------

__global__ __launch_bounds__(256) void cmc_count(
    const uint32_t* __restrict__ maskw, float* __restrict__ cntrow) {
  const int wid = (blockIdx.x * 256 + threadIdx.x) >> 6;  // one wave per row
  const int l = threadIdx.x & 63;
  const int p = wid >> 12;
  const int r = wid & 4095;
  const int mi = (p == 2) ? 1 : 0;
  const int mj = (p == 0) ? 1 : 2;
  int cnt = 0;
  #pragma unroll
  for (int h = 0; h < 2; ++h) {
    const int wd = h * 64 + l;
    uint32_t v = maskw[((size_t)mi * NB + r) * 128 + wd] |
                 maskw[((size_t)mj * NB + r) * 128 + wd];
    if ((r >> 5) == wd) v |= (1u << (r & 31));   // diagonal always kept
    cnt += __popc(v);
  }
  #pragma unroll
  for (int d = 1; d < 64; d <<= 1) cnt += __shfl_xor(cnt, d);
  if (l == 0) cntrow[p * NB + r] = (float)cnt;
}

// ---------- kernel 5: finalize ----------

__global__ __launch_bounds__(256) void cmc_final(
    const float* __restrict__ sumexp, const float* __restrict__ cntrow,
    const float* __restrict__ diagv, float* __restrict__ out) {
  const int tid = threadIdx.x;
  __shared__ float sred[8];
  float lsum = 0.f;
  for (int p = 0; p < 3; ++p) {
    float t = 0.f, c = 0.f;
    for (int r = tid; r < NB; r += 256) {
      const float cnt = cntrow[p * NB + r];
      if (cnt > 1.0f) {
        t += logf(sumexp[p * NB + r]) - diagv[p * NB + r];
        c += 1.f;
      }
    }
    #pragma unroll
    for (int d = 1; d < 64; d <<= 1) { t += __shfl_xor(t, d); c += __shfl_xor(c, d); }
    if ((tid & 63) == 0) { sred[(tid >> 6) * 2] = t; sred[(tid >> 6) * 2 + 1] = c; }
    __syncthreads();
    if (tid == 0) {
      const float tt = sred[0] + sred[2] + sred[4] + sred[6];
      const float cc = sred[1] + sred[3] + sred[5] + sred[7];
      lsum += (cc > 0.f) ? tt / fmaxf(cc, 1.f) : 0.f;
    }
    __syncthreads();
  }
  if (tid == 0) out[0] = lsum / 3.0f;
}

// ---------- launch ----------

extern "C" void kernel_launch(void* const* d_in, const int* in_sizes, int n_in,
                              void* d_out, int out_size, void* d_ws, size_t ws_size,
                              hipStream_t stream) {
  const float* in = (const float*)d_in[0];
  float* out = (float*)d_out;
  char* ws = (char*)d_ws;

  const size_t X8_BYTES = (size_t)3 * NB * ND;          // 12,582,912
  uint8_t* xf8  = (uint8_t*)ws;
  float* lnorm  = (float*)(ws + X8_BYTES);
  float* sumexp = lnorm + 3 * NB;
  float* cntrow = sumexp + 3 * NB;
  float* diagv  = cntrow + 3 * NB;
  uint32_t* maskw = (uint32_t*)(diagv + 3 * NB);        // [3][4096][128] = 6 MB

  hipMemsetAsync(sumexp, 0, (size_t)3 * NB * sizeof(float), stream);

  cmc_convert<<<3 * NB, 256, 0, stream>>>(in, xf8, lnorm);
  cmc_selfmask<<<dim3(NB / 128, NB / 128, 3), 256, 0, stream>>>(xf8, lnorm, maskw);
  cmc_pair<<<dim3(NB / 128, NB / 128, 3), 256, 0, stream>>>(xf8, lnorm, maskw, sumexp, diagv);
  cmc_count<<<3 * NB / 4, 256, 0, stream>>>(maskw, cntrow);
  cmc_final<<<1, 256, 0, stream>>>(sumexp, cntrow, diagv, out);
}